// Round 8
// baseline (488.023 us; speedup 1.0000x reference)
//
#include <hip/hip_runtime.h>
#include <stdint.h>

#define N_TOK 4096
#define TD 384
#define KNB 64
#define PD 128
#define HD 256
#define NPROJ 256  // 2*PD
#define RPB 32     // rows per tile
#define TPB_LN 16  // tokens per block in ln kernel
#define TILES_PER_BLK 8

// ---- workspace layout (bytes) ----
// [0,64) int flags[16]; [64,661056) f32 canon; [663552,991232) bf16 weights;
// [1<<20, +2MB) projb bf16 [4096][256]
#define CAN_LN_G 0
#define CAN_LN_B 384
#define CAN_WX   768
#define CAN_T_G  99072
#define CAN_T_B  99200
#define CAN_W1   99328
#define CAN_B1   132096
#define CAN_W2   132352
#define CAN_B2   165120
#define CAN_TOTAL 165248

#define BW_OFF   663552
#define WXT_OFF  0        // WxT [256][384]
#define W1T_OFF  98304    // W1T [256][128]
#define W2T_OFF  131072   // W2T [128][256]
#define BW_TOTAL 163840
#define PROJ_OFF (1 << 20)

typedef __attribute__((ext_vector_type(8))) short bf16x8;
typedef __attribute__((ext_vector_type(4))) short s16x4;
typedef __attribute__((ext_vector_type(4))) float f32x4;
typedef __attribute__((ext_vector_type(2))) unsigned int u32x2;
typedef __attribute__((ext_vector_type(4))) unsigned int u32x4;

static __device__ __forceinline__ float bf2f(unsigned short u) {
    return __uint_as_float(((unsigned int)u) << 16);
}
static __device__ __forceinline__ unsigned short f2bf(float f) {
    unsigned int x = __float_as_uint(f);
    return (unsigned short)((x + 0x7FFFu + ((x >> 16) & 1u)) >> 16);
}
static __device__ __forceinline__ float loadf(const void* p, int mode, int i) {
    return mode ? bf2f(((const unsigned short*)p)[i]) : ((const float*)p)[i];
}
// raw word of a bool element (any storage mode); nonzero == true for all modes
static __device__ __forceinline__ unsigned int flag_word(const void* p, int mode, int i) {
    if (mode == 0) return ((const unsigned int*)p)[i];
    if (mode == 1) return (unsigned int)((const unsigned char*)p)[i];
    if (mode == 2) return (unsigned int)((const unsigned short*)p)[i];
    return ((const unsigned int*)p)[i];
}
static __device__ __forceinline__ bool plaus16(unsigned int h) {
    if (h == 0u) return true;
    unsigned int e = (h >> 7) & 0xFFu;
    return (e >= 0x60u && e <= 0x9Fu);
}

__global__ __launch_bounds__(256) void detect_kernel(
        const void* __restrict__ x, const void* __restrict__ pair_rep,
        const void* __restrict__ mask, const void* __restrict__ slot,
        int* __restrict__ flags) {
    const int t = threadIdx.x;
    const int wave = t >> 6, lane = t & 63;
    if (wave < 2) {
        const unsigned int* w = (const unsigned int*)(wave == 0 ? x : pair_rep);
        unsigned int v = w[lane];
        bool pl = plaus16(v & 0xFFFFu) && plaus16(v >> 16);
        unsigned long long b = __ballot(pl);
        if (lane == 0) flags[2 + wave] = (__popcll(b) >= 56) ? 1 : 0;
    } else {
        const unsigned int* w = (const unsigned int*)(wave == 2 ? mask : slot);
        bool ok01 = true, okbf = true, anybf_lo = false;
        #pragma unroll
        for (int j = 0; j < 4; ++j) {
            unsigned int v = w[lane * 4 + j];
            if (v > 1u) ok01 = false;
            unsigned int h0 = v & 0xFFFFu, h1 = v >> 16;
            if (!(h0 == 0u || h0 == 0x3F80u)) okbf = false;
            if (!(h1 == 0u || h1 == 0x3F80u)) okbf = false;
            if (h0 == 0x3F80u) anybf_lo = true;
        }
        unsigned long long b01 = __ballot(ok01);
        unsigned long long bbf = __ballot(okbf);
        unsigned long long bev = __ballot(anybf_lo);
        if (lane == 0) {
            int mode;
            if (b01 == ~0ull) mode = 0;
            else if (bbf == ~0ull) mode = (bev != 0ull) ? 2 : 3;
            else mode = 1;
            flags[wave - 2] = mode;
        }
    }
}

// f32 canon of 9 weight tensors + bf16 transposed Wx/W1/W2, one kernel.
__global__ __launch_bounds__(256) void prep_kernel(
        const void* p0, const void* p1, const void* p2, const void* p3,
        const void* p4, const void* p5, const void* p6, const void* p7,
        const void* p8, const int* __restrict__ flags,
        float* __restrict__ dstf, short* __restrict__ dstb) {
    const int mode = flags[2];
    int e = blockIdx.x * 256 + threadIdx.x;
    if (e < CAN_TOTAL) {
        const int offs[9] = {CAN_LN_G, CAN_LN_B, CAN_WX, CAN_T_G, CAN_T_B,
                             CAN_W1, CAN_B1, CAN_W2, CAN_B2};
        int s = 0;
        #pragma unroll
        for (int i = 1; i < 9; ++i) if (e >= offs[i]) s = i;
        const int local = e - offs[s];
        const void* p = (s == 0) ? p0 : (s == 1) ? p1 : (s == 2) ? p2 :
                        (s == 3) ? p3 : (s == 4) ? p4 : (s == 5) ? p5 :
                        (s == 6) ? p6 : (s == 7) ? p7 : p8;
        dstf[e] = loadf(p, mode, local);
    } else {
        int e2 = e - CAN_TOTAL;
        if (e2 >= BW_TOTAL) return;
        int src; const void* p;
        if (e2 < W1T_OFF)      { int n = e2 / TD, k = e2 - n * TD;           p = p2; src = k * NPROJ + n; }
        else if (e2 < W2T_OFF) { int l = e2 - W1T_OFF; int n = l >> 7, k = l & 127; p = p5; src = k * HD + n; }
        else                   { int l = e2 - W2T_OFF; int n = l >> 8, k = l & 255; p = p7; src = k * PD + n; }
        dstb[e2] = (short)f2bf(loadf(p, mode, src));
    }
}

// LN over TD=384 for 16 tokens, then proj = xn @ Wx via MFMA; output bf16.
__global__ __launch_bounds__(256) void ln_proj_mfma(
        const void* __restrict__ x,
        const float* __restrict__ canon,
        const short* __restrict__ wxt,
        const int* __restrict__ flags,
        unsigned short* __restrict__ projb) {
    __shared__ __align__(16) short xnb[TPB_LN][TD + 8];
    const int t = threadIdx.x, wv = t >> 6, lane = t & 63;
    const int tok0 = blockIdx.x * TPB_LN;
    const int xm = flags[2];

    float g[6], bv[6];
    #pragma unroll
    for (int j = 0; j < 6; ++j) {
        g[j]  = canon[CAN_LN_G + lane + 64 * j];
        bv[j] = canon[CAN_LN_B + lane + 64 * j];
    }
    #pragma unroll
    for (int rr = 0; rr < TPB_LN / 4; ++rr) {
        const int r = wv * (TPB_LN / 4) + rr;
        float v[6], s = 0.f, sq = 0.f;
        #pragma unroll
        for (int j = 0; j < 6; ++j) {
            v[j] = loadf(x, xm, (tok0 + r) * TD + lane + 64 * j);
            s += v[j]; sq += v[j] * v[j];
        }
        #pragma unroll
        for (int off = 32; off > 0; off >>= 1) {
            s += __shfl_down(s, off); sq += __shfl_down(sq, off);
        }
        s = __shfl(s, 0); sq = __shfl(sq, 0);
        const float mu = s * (1.f / TD);
        const float var = sq * (1.f / TD) - mu * mu;
        const float rs = rsqrtf(var + 1e-5f);
        #pragma unroll
        for (int j = 0; j < 6; ++j)
            xnb[r][lane + 64 * j] = (short)f2bf((v[j] - mu) * rs * g[j] + bv[j]);
    }
    __syncthreads();

    const int qr = lane >> 4, ln16 = lane & 15;
    const int n0 = wv * 64;
    f32x4 acc[4];
    #pragma unroll
    for (int nt = 0; nt < 4; ++nt) acc[nt] = f32x4{0.f, 0.f, 0.f, 0.f};
    #pragma unroll
    for (int ks = 0; ks < 12; ++ks) {
        const int k0 = ks * 32 + qr * 8;
        bf16x8 a = *(const bf16x8*)&xnb[ln16][k0];
        #pragma unroll
        for (int nt = 0; nt < 4; ++nt) {
            bf16x8 b = *(const bf16x8*)(wxt + (n0 + nt * 16 + ln16) * TD + k0);
            acc[nt] = __builtin_amdgcn_mfma_f32_16x16x32_bf16(a, b, acc[nt], 0, 0, 0);
        }
    }
    #pragma unroll
    for (int nt = 0; nt < 4; ++nt) {
        const int c = n0 + nt * 16 + ln16;
        #pragma unroll
        for (int r = 0; r < 4; ++r)
            projb[(tok0 + qr * 4 + r) * NPROJ + c] = f2bf(acc[nt][r]);
    }
}

// Persistent pipelined pair kernel. Linear-I/O + register-resident weights.
//   LESSON (r7): (256,4) capped VGPR at exactly the kernel's natural 128 -> the
//   allocator REMATERIALIZED the loop-invariant weight loads back into the loop
//   (VGPR 64, FETCH 640MB, 244us — the r1 profile). (256,3) caps at ~170, leaving
//   slack so weights stay resident (~128 VGPR); HW residency is computed from
//   ACTUAL usage: 128 VGPR -> 4 waves/EU -> 4 blocks/CU (LDS 137KB<=160, grid=4/CU).
__global__ __launch_bounds__(256, 3) void pair_kernel(
        const void* __restrict__ pair_rep,
        const void* __restrict__ mask,
        const int*  __restrict__ nbr,
        const void* __restrict__ slot,
        const float* __restrict__ canon,
        const short* __restrict__ w1t,
        const short* __restrict__ w2t,
        const unsigned short* __restrict__ projb,
        const int* __restrict__ flags,
        float* __restrict__ out) {
    union ZU {
        short znb[RPB][PD + 8];   // 8704 B: raw z then LN(z), bf16 (phases 2-4)
        float ol[RPB][PD + 4];    // 16896 B: transition output O, f32 (phase 5+)
    };
    __shared__ __align__(16) ZU U;
    __shared__ __align__(16) short Hb[RPB][HD + 8];    // 16.9 KB relu hidden, bf16
    __shared__ float pmf2[2][RPB];

    const int t = threadIdx.x;
    const int wv = t >> 6, lane = t & 63, qr = lane >> 4, ln16 = lane & 15;
    const int lr = t >> 5;        // linear row slot 0..7
    const int c4 = t & 31;        // float4 column chunk (cols 4*c4 .. 4*c4+3)
    const int mmode = flags[0], smode = flags[1], prm = flags[3];

    // ---- persistent B-fragments (loaded once; live across the whole tile loop)
    bf16x8 bw1[16];   // phase-4 W1T frags: [ks*4+nt]
    bf16x8 bw2[16];   // phase-5 W2T frags: [ks*2+nt]
    #pragma unroll
    for (int ks = 0; ks < 4; ++ks)
        #pragma unroll
        for (int nt = 0; nt < 4; ++nt)
            bw1[ks * 4 + nt] = *(const bf16x8*)(
                w1t + (wv * 64 + nt * 16 + ln16) * PD + ks * 32 + qr * 8);
    #pragma unroll
    for (int ks = 0; ks < 8; ++ks)
        #pragma unroll
        for (int nt = 0; nt < 2; ++nt)
            bw2[ks * 2 + nt] = *(const bf16x8*)(
                w2t + (wv * 32 + nt * 16 + ln16) * HD + ks * 32 + qr * 8);

    // prefetch registers (raw words, converted at consume)
    int idxq[4], mIdx = 0;
    u32x4 pru[4];                 // pair_rep: f32 mode uses 4 words, bf16 mode 2
    u32x2 pgu[4];                 // gathered xp1 row chunk (4 bf16)
    u32x2 x2u;                    // xp2 chunk (4 bf16), same for all rows of tile
    unsigned int wmn = 0, wmi = 0, wsl = 0;

    const int tile0 = blockIdx.x * TILES_PER_BLK;

    // ---------- prologue: full prefetch of tile0 ----------
    {
        const int row0 = tile0 * RPB, n = row0 >> 6, k0 = row0 & (KNB - 1);
        #pragma unroll
        for (int q = 0; q < 4; ++q) idxq[q] = nbr[n * KNB + k0 + 8 * q + lr];
        x2u = *(const u32x2*)(projb + n * NPROJ + PD + 4 * c4);
        #pragma unroll
        for (int q = 0; q < 4; ++q)
            pgu[q] = *(const u32x2*)(projb + idxq[q] * NPROJ + 4 * c4);
        if (prm) {
            const unsigned short* pr = (const unsigned short*)pair_rep;
            #pragma unroll
            for (int q = 0; q < 4; ++q) {
                u32x2 v = __builtin_nontemporal_load(
                    (const u32x2*)(pr + (row0 + 8 * q + lr) * PD + 4 * c4));
                pru[q][0] = v[0]; pru[q][1] = v[1];
            }
        } else {
            const float* pr = (const float*)pair_rep;
            #pragma unroll
            for (int q = 0; q < 4; ++q)
                pru[q] = __builtin_nontemporal_load(
                    (const u32x4*)(pr + (row0 + 8 * q + lr) * PD + 4 * c4));
        }
        if (t < RPB) {
            mIdx = nbr[n * KNB + k0 + t];
            wmn = flag_word(mask, mmode, n);
            wmi = flag_word(mask, mmode, mIdx);
            wsl = flag_word(slot, smode, n * KNB + k0 + t);
            pmf2[0][t] = (wmn && wmi && wsl) ? 1.f : 0.f;
        }
    }

    #pragma unroll 1
    for (int i = 0; i < TILES_PER_BLK; ++i) {
        const int tile = tile0 + i;
        const int cur = i & 1, nxt = cur ^ 1;
        const int row0 = tile * RPB;
        const int tn = (i + 1 < TILES_PER_BLK) ? tile + 1 : tile;  // clamp (dup loads unused)
        const int row0n = tn * RPB, nn = row0n >> 6, k0n = row0n & (KNB - 1);

        __syncthreads();  // T: LDS reusable (coop store of prev tile done), pmf2[cur] ready

        // ---- phase 2: z = (pair + xp2 + xp1[idx])*pm ; residual in zq regs, bf16 to znb
        f32x4 zq[4];
        {
            float x2v[4];
            x2v[0] = bf2f((unsigned short)(x2u[0] & 0xFFFFu));
            x2v[1] = bf2f((unsigned short)(x2u[0] >> 16));
            x2v[2] = bf2f((unsigned short)(x2u[1] & 0xFFFFu));
            x2v[3] = bf2f((unsigned short)(x2u[1] >> 16));
            #pragma unroll
            for (int q = 0; q < 4; ++q) {
                const int row = 8 * q + lr;
                const float pm = pmf2[cur][row];
                float a[4], gg[4];
                gg[0] = bf2f((unsigned short)(pgu[q][0] & 0xFFFFu));
                gg[1] = bf2f((unsigned short)(pgu[q][0] >> 16));
                gg[2] = bf2f((unsigned short)(pgu[q][1] & 0xFFFFu));
                gg[3] = bf2f((unsigned short)(pgu[q][1] >> 16));
                if (prm) {
                    a[0] = bf2f((unsigned short)(pru[q][0] & 0xFFFFu));
                    a[1] = bf2f((unsigned short)(pru[q][0] >> 16));
                    a[2] = bf2f((unsigned short)(pru[q][1] & 0xFFFFu));
                    a[3] = bf2f((unsigned short)(pru[q][1] >> 16));
                } else {
                    a[0] = __uint_as_float(pru[q][0]);
                    a[1] = __uint_as_float(pru[q][1]);
                    a[2] = __uint_as_float(pru[q][2]);
                    a[3] = __uint_as_float(pru[q][3]);
                }
                s16x4 zs;
                #pragma unroll
                for (int e = 0; e < 4; ++e) {
                    const float z = (a[e] + x2v[e] + gg[e]) * pm;
                    zq[q][e] = z;
                    zs[e] = (short)f2bf(z);
                }
                *(s16x4*)&U.znb[row][4 * c4] = zs;
            }
        }

        // issue next-tile index loads (consumed at sync C prefetch)
        #pragma unroll
        for (int q = 0; q < 4; ++q) idxq[q] = nbr[nn * KNB + k0n + 8 * q + lr];
        if (t < RPB) mIdx = nbr[nn * KNB + k0n + t];

        __syncthreads();  // A

        // ---- phase 3: in-place per-row LN on znb (wave owns rows wv*8..+8)
        {
            const float g0 = canon[CAN_T_G + lane], g1 = canon[CAN_T_G + lane + 64];
            const float b0 = canon[CAN_T_B + lane], b1v = canon[CAN_T_B + lane + 64];
            #pragma unroll
            for (int rr = 0; rr < 8; ++rr) {
                const int r = wv * 8 + rr;
                const float a0 = bf2f((unsigned short)U.znb[r][lane]);
                const float a1 = bf2f((unsigned short)U.znb[r][lane + 64]);
                float s = a0 + a1, sq = a0 * a0 + a1 * a1;
                #pragma unroll
                for (int off = 32; off > 0; off >>= 1) {
                    s += __shfl_down(s, off); sq += __shfl_down(sq, off);
                }
                s = __shfl(s, 0); sq = __shfl(sq, 0);
                const float mu = s * (1.f / PD);
                const float var = sq * (1.f / PD) - mu * mu;
                const float rs = rsqrtf(var + 1e-5f);
                U.znb[r][lane]      = (short)f2bf((a0 - mu) * rs * g0 + b0);
                U.znb[r][lane + 64] = (short)f2bf((a1 - mu) * rs * g1 + b1v);
            }
        }
        __syncthreads();  // B

        // ---- phase 4: H = relu(zn @ W1 + b1)  (B-frags in regs, no global loads)
        {
            f32x4 acc1[2][4];
            #pragma unroll
            for (int mt = 0; mt < 2; ++mt)
                #pragma unroll
                for (int nt = 0; nt < 4; ++nt) acc1[mt][nt] = f32x4{0.f, 0.f, 0.f, 0.f};
            #pragma unroll
            for (int ks = 0; ks < 4; ++ks) {
                const int k0 = ks * 32 + qr * 8;
                bf16x8 a0 = *(const bf16x8*)&U.znb[ln16][k0];
                bf16x8 a1 = *(const bf16x8*)&U.znb[16 + ln16][k0];
                #pragma unroll
                for (int nt = 0; nt < 4; ++nt) {
                    acc1[0][nt] = __builtin_amdgcn_mfma_f32_16x16x32_bf16(a0, bw1[ks * 4 + nt], acc1[0][nt], 0, 0, 0);
                    acc1[1][nt] = __builtin_amdgcn_mfma_f32_16x16x32_bf16(a1, bw1[ks * 4 + nt], acc1[1][nt], 0, 0, 0);
                }
            }
            const int n0 = wv * 64;
            #pragma unroll
            for (int nt = 0; nt < 4; ++nt) {
                const int c = n0 + nt * 16 + ln16;
                const float bb = canon[CAN_B1 + c];
                #pragma unroll
                for (int mt = 0; mt < 2; ++mt)
                    #pragma unroll
                    for (int r = 0; r < 4; ++r) {
                        const float h = acc1[mt][nt][r] + bb;
                        Hb[mt * 16 + qr * 4 + r][c] = (short)f2bf(h > 0.f ? h : 0.f);
                    }
            }
        }
        __syncthreads();  // C  (znb is DEAD from here; U.ol may be written)

        // ---- issue prefetch for tile tn (hidden behind phase 5)
        x2u = *(const u32x2*)(projb + nn * NPROJ + PD + 4 * c4);
        #pragma unroll
        for (int q = 0; q < 4; ++q)
            pgu[q] = *(const u32x2*)(projb + idxq[q] * NPROJ + 4 * c4);
        if (prm) {
            const unsigned short* pr = (const unsigned short*)pair_rep;
            #pragma unroll
            for (int q = 0; q < 4; ++q) {
                u32x2 v = __builtin_nontemporal_load(
                    (const u32x2*)(pr + (row0n + 8 * q + lr) * PD + 4 * c4));
                pru[q][0] = v[0]; pru[q][1] = v[1];
            }
        } else {
            const float* pr = (const float*)pair_rep;
            #pragma unroll
            for (int q = 0; q < 4; ++q)
                pru[q] = __builtin_nontemporal_load(
                    (const u32x4*)(pr + (row0n + 8 * q + lr) * PD + 4 * c4));
        }
        if (t < RPB) {
            wmn = flag_word(mask, mmode, nn);
            wmi = flag_word(mask, mmode, mIdx);
            wsl = flag_word(slot, smode, nn * KNB + k0n + t);
        }

        // ---- phase 5: O = H @ W2 + b2; stage O*pm into U.ol (f32, MFMA layout)
        {
            f32x4 acc2[2][2];
            #pragma unroll
            for (int mt = 0; mt < 2; ++mt)
                #pragma unroll
                for (int nt = 0; nt < 2; ++nt) acc2[mt][nt] = f32x4{0.f, 0.f, 0.f, 0.f};
            #pragma unroll
            for (int ks = 0; ks < 8; ++ks) {
                const int k0 = ks * 32 + qr * 8;
                bf16x8 a0 = *(const bf16x8*)&Hb[ln16][k0];
                bf16x8 a1 = *(const bf16x8*)&Hb[16 + ln16][k0];
                #pragma unroll
                for (int nt = 0; nt < 2; ++nt) {
                    acc2[0][nt] = __builtin_amdgcn_mfma_f32_16x16x32_bf16(a0, bw2[ks * 2 + nt], acc2[0][nt], 0, 0, 0);
                    acc2[1][nt] = __builtin_amdgcn_mfma_f32_16x16x32_bf16(a1, bw2[ks * 2 + nt], acc2[1][nt], 0, 0, 0);
                }
            }
            const int p0w = wv * 32;
            #pragma unroll
            for (int nt = 0; nt < 2; ++nt) {
                const int p = p0w + nt * 16 + ln16;
                const float bb = canon[CAN_B2 + p];
                #pragma unroll
                for (int mt = 0; mt < 2; ++mt)
                    #pragma unroll
                    for (int r = 0; r < 4; ++r) {
                        const int row = mt * 16 + qr * 4 + r;
                        const float pm = pmf2[cur][row];
                        U.ol[row][p] = (acc2[mt][nt][r] + bb) * pm;
                    }
            }
        }
        if (t < RPB) pmf2[nxt][t] = (wmn && wmi && wsl) ? 1.f : 0.f;

        __syncthreads();  // D: U.ol complete

        // ---- coop store: out = z + O, full-line float4 per lane, nontemporal
        #pragma unroll
        for (int q = 0; q < 4; ++q) {
            const int row = 8 * q + lr;
            f32x4 o = *(const f32x4*)&U.ol[row][4 * c4];
            f32x4 ov = zq[q] + o;
            __builtin_nontemporal_store(ov, (f32x4*)&out[(row0 + row) * PD + 4 * c4]);
        }
    }
}

extern "C" void kernel_launch(void* const* d_in, const int* in_sizes, int n_in,
                              void* d_out, int out_size, void* d_ws, size_t ws_size,
                              hipStream_t stream) {
    const void* x        = d_in[0];
    const void* pair_rep = d_in[1];
    const void* mask     = d_in[2];
    const int*  nbr      = (const int*)d_in[3];
    const void* slot     = d_in[4];
    float* out = (float*)d_out;

    int*   flags = (int*)d_ws;
    float* canon = (float*)((char*)d_ws + 64);
    short* bw    = (short*)((char*)d_ws + BW_OFF);
    const short* wxt = bw + WXT_OFF;
    const short* w1t = bw + W1T_OFF;
    const short* w2t = bw + W2T_OFF;
    unsigned short* projb = (unsigned short*)((char*)d_ws + PROJ_OFF);

    detect_kernel<<<1, 256, 0, stream>>>(x, pair_rep, mask, slot, flags);
    prep_kernel<<<(CAN_TOTAL + BW_TOTAL + 255) / 256, 256, 0, stream>>>(
        d_in[5], d_in[6], d_in[7], d_in[8], d_in[9], d_in[10], d_in[11],
        d_in[12], d_in[13], flags, canon, bw);
    ln_proj_mfma<<<N_TOK / TPB_LN, 256, 0, stream>>>(x, canon, wxt, flags, projb);
    pair_kernel<<<(N_TOK * KNB) / (RPB * TILES_PER_BLK), 256, 0, stream>>>(
        pair_rep, mask, nbr, slot, canon, w1t, w2t, projb, flags, out);
}

// Round 10
// 329.639 us; speedup vs baseline: 1.4805x; 1.4805x over previous
//
#include <hip/hip_runtime.h>
#include <stdint.h>

#define N_TOK 4096
#define TD 384
#define KNB 64
#define PD 128
#define HD 256
#define NPROJ 256  // 2*PD
#define RPB 32     // rows per tile
#define TPB_LN 16  // tokens per block in ln kernel
#define TILES_PER_BLK 8

// ---- workspace layout (bytes) ----
// [0,64) int flags[16]; [64,661056) f32 canon; [663552,991232) bf16 weights;
// [1<<20, +2MB) projb bf16 [4096][256]
#define CAN_LN_G 0
#define CAN_LN_B 384
#define CAN_WX   768
#define CAN_T_G  99072
#define CAN_T_B  99200
#define CAN_W1   99328
#define CAN_B1   132096
#define CAN_W2   132352
#define CAN_B2   165120
#define CAN_TOTAL 165248

#define BW_OFF   663552
#define WXT_OFF  0        // WxT [256][384]
#define W1T_OFF  98304    // W1T [256][128]
#define W2T_OFF  131072   // W2T [128][256]
#define BW_TOTAL 163840
#define PROJ_OFF (1 << 20)

typedef __attribute__((ext_vector_type(8))) short bf16x8;
typedef __attribute__((ext_vector_type(4))) short s16x4;
typedef __attribute__((ext_vector_type(4))) float f32x4;
typedef __attribute__((ext_vector_type(2))) unsigned int u32x2;
typedef __attribute__((ext_vector_type(4))) unsigned int u32x4;

static __device__ __forceinline__ float bf2f(unsigned short u) {
    return __uint_as_float(((unsigned int)u) << 16);
}
static __device__ __forceinline__ unsigned short f2bf(float f) {
    unsigned int x = __float_as_uint(f);
    return (unsigned short)((x + 0x7FFFu + ((x >> 16) & 1u)) >> 16);
}
static __device__ __forceinline__ float loadf(const void* p, int mode, int i) {
    return mode ? bf2f(((const unsigned short*)p)[i]) : ((const float*)p)[i];
}
// raw word of a bool element (any storage mode); nonzero == true for all modes
static __device__ __forceinline__ unsigned int flag_word(const void* p, int mode, int i) {
    if (mode == 0) return ((const unsigned int*)p)[i];
    if (mode == 1) return (unsigned int)((const unsigned char*)p)[i];
    if (mode == 2) return (unsigned int)((const unsigned short*)p)[i];
    return ((const unsigned int*)p)[i];
}
static __device__ __forceinline__ bool plaus16(unsigned int h) {
    if (h == 0u) return true;
    unsigned int e = (h >> 7) & 0xFFu;
    return (e >= 0x60u && e <= 0x9Fu);
}

__global__ __launch_bounds__(256) void detect_kernel(
        const void* __restrict__ x, const void* __restrict__ pair_rep,
        const void* __restrict__ mask, const void* __restrict__ slot,
        int* __restrict__ flags) {
    const int t = threadIdx.x;
    const int wave = t >> 6, lane = t & 63;
    if (wave < 2) {
        const unsigned int* w = (const unsigned int*)(wave == 0 ? x : pair_rep);
        unsigned int v = w[lane];
        bool pl = plaus16(v & 0xFFFFu) && plaus16(v >> 16);
        unsigned long long b = __ballot(pl);
        if (lane == 0) flags[2 + wave] = (__popcll(b) >= 56) ? 1 : 0;
    } else {
        const unsigned int* w = (const unsigned int*)(wave == 2 ? mask : slot);
        bool ok01 = true, okbf = true, anybf_lo = false;
        #pragma unroll
        for (int j = 0; j < 4; ++j) {
            unsigned int v = w[lane * 4 + j];
            if (v > 1u) ok01 = false;
            unsigned int h0 = v & 0xFFFFu, h1 = v >> 16;
            if (!(h0 == 0u || h0 == 0x3F80u)) okbf = false;
            if (!(h1 == 0u || h1 == 0x3F80u)) okbf = false;
            if (h0 == 0x3F80u) anybf_lo = true;
        }
        unsigned long long b01 = __ballot(ok01);
        unsigned long long bbf = __ballot(okbf);
        unsigned long long bev = __ballot(anybf_lo);
        if (lane == 0) {
            int mode;
            if (b01 == ~0ull) mode = 0;
            else if (bbf == ~0ull) mode = (bev != 0ull) ? 2 : 3;
            else mode = 1;
            flags[wave - 2] = mode;
        }
    }
}

// f32 canon of 9 weight tensors + bf16 transposed Wx/W1/W2, one kernel.
__global__ __launch_bounds__(256) void prep_kernel(
        const void* p0, const void* p1, const void* p2, const void* p3,
        const void* p4, const void* p5, const void* p6, const void* p7,
        const void* p8, const int* __restrict__ flags,
        float* __restrict__ dstf, short* __restrict__ dstb) {
    const int mode = flags[2];
    int e = blockIdx.x * 256 + threadIdx.x;
    if (e < CAN_TOTAL) {
        const int offs[9] = {CAN_LN_G, CAN_LN_B, CAN_WX, CAN_T_G, CAN_T_B,
                             CAN_W1, CAN_B1, CAN_W2, CAN_B2};
        int s = 0;
        #pragma unroll
        for (int i = 1; i < 9; ++i) if (e >= offs[i]) s = i;
        const int local = e - offs[s];
        const void* p = (s == 0) ? p0 : (s == 1) ? p1 : (s == 2) ? p2 :
                        (s == 3) ? p3 : (s == 4) ? p4 : (s == 5) ? p5 :
                        (s == 6) ? p6 : (s == 7) ? p7 : p8;
        dstf[e] = loadf(p, mode, local);
    } else {
        int e2 = e - CAN_TOTAL;
        if (e2 >= BW_TOTAL) return;
        int src; const void* p;
        if (e2 < W1T_OFF)      { int n = e2 / TD, k = e2 - n * TD;           p = p2; src = k * NPROJ + n; }
        else if (e2 < W2T_OFF) { int l = e2 - W1T_OFF; int n = l >> 7, k = l & 127; p = p5; src = k * HD + n; }
        else                   { int l = e2 - W2T_OFF; int n = l >> 8, k = l & 255; p = p7; src = k * PD + n; }
        dstb[e2] = (short)f2bf(loadf(p, mode, src));
    }
}

// LN over TD=384 for 16 tokens, then proj = xn @ Wx via MFMA; output bf16.
__global__ __launch_bounds__(256) void ln_proj_mfma(
        const void* __restrict__ x,
        const float* __restrict__ canon,
        const short* __restrict__ wxt,
        const int* __restrict__ flags,
        unsigned short* __restrict__ projb) {
    __shared__ __align__(16) short xnb[TPB_LN][TD + 8];
    const int t = threadIdx.x, wv = t >> 6, lane = t & 63;
    const int tok0 = blockIdx.x * TPB_LN;
    const int xm = flags[2];

    float g[6], bv[6];
    #pragma unroll
    for (int j = 0; j < 6; ++j) {
        g[j]  = canon[CAN_LN_G + lane + 64 * j];
        bv[j] = canon[CAN_LN_B + lane + 64 * j];
    }
    #pragma unroll
    for (int rr = 0; rr < TPB_LN / 4; ++rr) {
        const int r = wv * (TPB_LN / 4) + rr;
        float v[6], s = 0.f, sq = 0.f;
        #pragma unroll
        for (int j = 0; j < 6; ++j) {
            v[j] = loadf(x, xm, (tok0 + r) * TD + lane + 64 * j);
            s += v[j]; sq += v[j] * v[j];
        }
        #pragma unroll
        for (int off = 32; off > 0; off >>= 1) {
            s += __shfl_down(s, off); sq += __shfl_down(sq, off);
        }
        s = __shfl(s, 0); sq = __shfl(sq, 0);
        const float mu = s * (1.f / TD);
        const float var = sq * (1.f / TD) - mu * mu;
        const float rs = rsqrtf(var + 1e-5f);
        #pragma unroll
        for (int j = 0; j < 6; ++j)
            xnb[r][lane + 64 * j] = (short)f2bf((v[j] - mu) * rs * g[j] + bv[j]);
    }
    __syncthreads();

    const int qr = lane >> 4, ln16 = lane & 15;
    const int n0 = wv * 64;
    f32x4 acc[4];
    #pragma unroll
    for (int nt = 0; nt < 4; ++nt) acc[nt] = f32x4{0.f, 0.f, 0.f, 0.f};
    #pragma unroll
    for (int ks = 0; ks < 12; ++ks) {
        const int k0 = ks * 32 + qr * 8;
        bf16x8 a = *(const bf16x8*)&xnb[ln16][k0];
        #pragma unroll
        for (int nt = 0; nt < 4; ++nt) {
            bf16x8 b = *(const bf16x8*)(wxt + (n0 + nt * 16 + ln16) * TD + k0);
            acc[nt] = __builtin_amdgcn_mfma_f32_16x16x32_bf16(a, b, acc[nt], 0, 0, 0);
        }
    }
    #pragma unroll
    for (int nt = 0; nt < 4; ++nt) {
        const int c = n0 + nt * 16 + ln16;
        #pragma unroll
        for (int r = 0; r < 4; ++r)
            projb[(tok0 + qr * 4 + r) * NPROJ + c] = f2bf(acc[nt][r]);
    }
}

// Persistent pipelined pair kernel. Linear-I/O + register-resident weights.
//   (256,2) is the KNOWN-GOOD allocator regime (r4: VGPR=128, weights resident,
//   FETCH 79MB, 133us). LESSONS r7/r8: (256,4)/(256,3) caps trigger weight-load
//   rematerialization (FETCH 640/335MB) — do not tighten the bound.
//   This version folds the z-LN into phase 2 (row r=8q+lr is owned by the 32
//   contiguous lanes t in [32*lr,32*lr+32): 5-step __shfl_xor on f32 z in regs)
//   and de-unions znb/ol, cutting barriers/tile 5 -> 3 (A,C,D; no T, no B) and
//   deleting the phase-3 LDS round trip.
__global__ __launch_bounds__(256, 2) void pair_kernel(
        const void* __restrict__ pair_rep,
        const void* __restrict__ mask,
        const int*  __restrict__ nbr,
        const void* __restrict__ slot,
        const float* __restrict__ canon,
        const short* __restrict__ w1t,
        const short* __restrict__ w2t,
        const unsigned short* __restrict__ projb,
        const int* __restrict__ flags,
        float* __restrict__ out) {
    __shared__ __align__(16) short znb[RPB][PD + 8];   //  8.7 KB LN(z) bf16
    __shared__ __align__(16) float ol[RPB][PD + 4];    // 16.9 KB transition out f32
    __shared__ __align__(16) short Hb[RPB][HD + 8];    // 16.9 KB relu hidden bf16
    __shared__ float pmf2[2][RPB];

    const int t = threadIdx.x;
    const int wv = t >> 6, lane = t & 63, qr = lane >> 4, ln16 = lane & 15;
    const int lr = t >> 5;        // linear row slot 0..7
    const int c4 = t & 31;        // float4 column chunk (cols 4*c4 .. 4*c4+3)
    const int mmode = flags[0], smode = flags[1], prm = flags[3];

    // ---- persistent B-fragments (loaded once; live across the whole tile loop)
    bf16x8 bw1[16];   // phase-4 W1T frags: [ks*4+nt]
    bf16x8 bw2[16];   // phase-5 W2T frags: [ks*2+nt]
    #pragma unroll
    for (int ks = 0; ks < 4; ++ks)
        #pragma unroll
        for (int nt = 0; nt < 4; ++nt)
            bw1[ks * 4 + nt] = *(const bf16x8*)(
                w1t + (wv * 64 + nt * 16 + ln16) * PD + ks * 32 + qr * 8);
    #pragma unroll
    for (int ks = 0; ks < 8; ++ks)
        #pragma unroll
        for (int nt = 0; nt < 2; ++nt)
            bw2[ks * 2 + nt] = *(const bf16x8*)(
                w2t + (wv * 32 + nt * 16 + ln16) * HD + ks * 32 + qr * 8);

    // per-thread LN params for cols 4*c4..4*c4+3 (loop-invariant)
    float tg[4], tb[4];
    #pragma unroll
    for (int e = 0; e < 4; ++e) {
        tg[e] = canon[CAN_T_G + 4 * c4 + e];
        tb[e] = canon[CAN_T_B + 4 * c4 + e];
    }

    // prefetch registers (raw words, converted at consume)
    int idxq[4], mIdx = 0;
    u32x4 pru[4];                 // pair_rep: f32 mode uses 4 words, bf16 mode 2
    u32x2 pgu[4];                 // gathered xp1 row chunk (4 bf16)
    u32x2 x2u;                    // xp2 chunk (4 bf16), same for all rows of tile
    unsigned int wmn = 0, wmi = 0, wsl = 0;

    const int tile0 = blockIdx.x * TILES_PER_BLK;

    // ---------- prologue: full prefetch of tile0 ----------
    {
        const int row0 = tile0 * RPB, n = row0 >> 6, k0 = row0 & (KNB - 1);
        #pragma unroll
        for (int q = 0; q < 4; ++q) idxq[q] = nbr[n * KNB + k0 + 8 * q + lr];
        x2u = *(const u32x2*)(projb + n * NPROJ + PD + 4 * c4);
        #pragma unroll
        for (int q = 0; q < 4; ++q)
            pgu[q] = *(const u32x2*)(projb + idxq[q] * NPROJ + 4 * c4);
        if (prm) {
            const unsigned short* pr = (const unsigned short*)pair_rep;
            #pragma unroll
            for (int q = 0; q < 4; ++q) {
                u32x2 v = __builtin_nontemporal_load(
                    (const u32x2*)(pr + (row0 + 8 * q + lr) * PD + 4 * c4));
                pru[q][0] = v[0]; pru[q][1] = v[1];
            }
        } else {
            const float* pr = (const float*)pair_rep;
            #pragma unroll
            for (int q = 0; q < 4; ++q)
                pru[q] = __builtin_nontemporal_load(
                    (const u32x4*)(pr + (row0 + 8 * q + lr) * PD + 4 * c4));
        }
        if (t < RPB) {
            mIdx = nbr[n * KNB + k0 + t];
            wmn = flag_word(mask, mmode, n);
            wmi = flag_word(mask, mmode, mIdx);
            wsl = flag_word(slot, smode, n * KNB + k0 + t);
            pmf2[0][t] = (wmn && wmi && wsl) ? 1.f : 0.f;
        }
    }
    __syncthreads();  // pmf2[0] visible before first phase-2 read

    #pragma unroll 1
    for (int i = 0; i < TILES_PER_BLK; ++i) {
        const int tile = tile0 + i;
        const int cur = i & 1, nxt = cur ^ 1;
        const int row0 = tile * RPB;
        const int tn = (i + 1 < TILES_PER_BLK) ? tile + 1 : tile;  // clamp (dup loads unused)
        const int row0n = tn * RPB, nn = row0n >> 6, k0n = row0n & (KNB - 1);

        // ---- phase 2 (+fused LN): z = (pair + xp2 + xp1[idx])*pm; row stats via
        //      half-wave shfl_xor on f32 z; write LN(z) bf16 to znb; keep z in zq.
        f32x4 zq[4];
        {
            float x2v[4];
            x2v[0] = bf2f((unsigned short)(x2u[0] & 0xFFFFu));
            x2v[1] = bf2f((unsigned short)(x2u[0] >> 16));
            x2v[2] = bf2f((unsigned short)(x2u[1] & 0xFFFFu));
            x2v[3] = bf2f((unsigned short)(x2u[1] >> 16));
            #pragma unroll
            for (int q = 0; q < 4; ++q) {
                const int row = 8 * q + lr;
                const float pm = pmf2[cur][row];
                float a[4], gg[4];
                gg[0] = bf2f((unsigned short)(pgu[q][0] & 0xFFFFu));
                gg[1] = bf2f((unsigned short)(pgu[q][0] >> 16));
                gg[2] = bf2f((unsigned short)(pgu[q][1] & 0xFFFFu));
                gg[3] = bf2f((unsigned short)(pgu[q][1] >> 16));
                if (prm) {
                    a[0] = bf2f((unsigned short)(pru[q][0] & 0xFFFFu));
                    a[1] = bf2f((unsigned short)(pru[q][0] >> 16));
                    a[2] = bf2f((unsigned short)(pru[q][1] & 0xFFFFu));
                    a[3] = bf2f((unsigned short)(pru[q][1] >> 16));
                } else {
                    a[0] = __uint_as_float(pru[q][0]);
                    a[1] = __uint_as_float(pru[q][1]);
                    a[2] = __uint_as_float(pru[q][2]);
                    a[3] = __uint_as_float(pru[q][3]);
                }
                float s = 0.f, sq = 0.f;
                #pragma unroll
                for (int e = 0; e < 4; ++e) {
                    const float z = (a[e] + x2v[e] + gg[e]) * pm;
                    zq[q][e] = z;
                    s += z; sq += z * z;
                }
                // reduce over the 32 lanes owning this row (offsets <32 stay in-group)
                #pragma unroll
                for (int off = 16; off > 0; off >>= 1) {
                    s  += __shfl_xor(s, off);
                    sq += __shfl_xor(sq, off);
                }
                const float mu = s * (1.f / PD);
                const float var = sq * (1.f / PD) - mu * mu;
                const float rs = rsqrtf(var + 1e-5f);
                s16x4 zs;
                #pragma unroll
                for (int e = 0; e < 4; ++e)
                    zs[e] = (short)f2bf((zq[q][e] - mu) * rs * tg[e] + tb[e]);
                *(s16x4*)&znb[row][4 * c4] = zs;
            }
        }

        // issue next-tile index loads (consumed at sync C prefetch)
        #pragma unroll
        for (int q = 0; q < 4; ++q) idxq[q] = nbr[nn * KNB + k0n + 8 * q + lr];
        if (t < RPB) mIdx = nbr[nn * KNB + k0n + t];

        __syncthreads();  // A: znb complete; also fences prev-iter ol reads vs phase 5

        // ---- phase 4: H = relu(zn @ W1 + b1)  (B-frags in regs, no global loads)
        {
            f32x4 acc1[2][4];
            #pragma unroll
            for (int mt = 0; mt < 2; ++mt)
                #pragma unroll
                for (int nt = 0; nt < 4; ++nt) acc1[mt][nt] = f32x4{0.f, 0.f, 0.f, 0.f};
            #pragma unroll
            for (int ks = 0; ks < 4; ++ks) {
                const int k0 = ks * 32 + qr * 8;
                bf16x8 a0 = *(const bf16x8*)&znb[ln16][k0];
                bf16x8 a1 = *(const bf16x8*)&znb[16 + ln16][k0];
                #pragma unroll
                for (int nt = 0; nt < 4; ++nt) {
                    acc1[0][nt] = __builtin_amdgcn_mfma_f32_16x16x32_bf16(a0, bw1[ks * 4 + nt], acc1[0][nt], 0, 0, 0);
                    acc1[1][nt] = __builtin_amdgcn_mfma_f32_16x16x32_bf16(a1, bw1[ks * 4 + nt], acc1[1][nt], 0, 0, 0);
                }
            }
            const int n0 = wv * 64;
            #pragma unroll
            for (int nt = 0; nt < 4; ++nt) {
                const int c = n0 + nt * 16 + ln16;
                const float bb = canon[CAN_B1 + c];
                #pragma unroll
                for (int mt = 0; mt < 2; ++mt)
                    #pragma unroll
                    for (int r = 0; r < 4; ++r) {
                        const float h = acc1[mt][nt][r] + bb;
                        Hb[mt * 16 + qr * 4 + r][c] = (short)f2bf(h > 0.f ? h : 0.f);
                    }
            }
        }
        __syncthreads();  // C: Hb complete

        // ---- issue prefetch for tile tn (hidden behind phase 5)
        x2u = *(const u32x2*)(projb + nn * NPROJ + PD + 4 * c4);
        #pragma unroll
        for (int q = 0; q < 4; ++q)
            pgu[q] = *(const u32x2*)(projb + idxq[q] * NPROJ + 4 * c4);
        if (prm) {
            const unsigned short* pr = (const unsigned short*)pair_rep;
            #pragma unroll
            for (int q = 0; q < 4; ++q) {
                u32x2 v = __builtin_nontemporal_load(
                    (const u32x2*)(pr + (row0n + 8 * q + lr) * PD + 4 * c4));
                pru[q][0] = v[0]; pru[q][1] = v[1];
            }
        } else {
            const float* pr = (const float*)pair_rep;
            #pragma unroll
            for (int q = 0; q < 4; ++q)
                pru[q] = __builtin_nontemporal_load(
                    (const u32x4*)(pr + (row0n + 8 * q + lr) * PD + 4 * c4));
        }
        if (t < RPB) {
            wmn = flag_word(mask, mmode, nn);
            wmi = flag_word(mask, mmode, mIdx);
            wsl = flag_word(slot, smode, nn * KNB + k0n + t);
        }

        // ---- phase 5: O = H @ W2 + b2; stage O*pm into ol (f32, MFMA layout)
        {
            f32x4 acc2[2][2];
            #pragma unroll
            for (int mt = 0; mt < 2; ++mt)
                #pragma unroll
                for (int nt = 0; nt < 2; ++nt) acc2[mt][nt] = f32x4{0.f, 0.f, 0.f, 0.f};
            #pragma unroll
            for (int ks = 0; ks < 8; ++ks) {
                const int k0 = ks * 32 + qr * 8;
                bf16x8 a0 = *(const bf16x8*)&Hb[ln16][k0];
                bf16x8 a1 = *(const bf16x8*)&Hb[16 + ln16][k0];
                #pragma unroll
                for (int nt = 0; nt < 2; ++nt) {
                    acc2[0][nt] = __builtin_amdgcn_mfma_f32_16x16x32_bf16(a0, bw2[ks * 2 + nt], acc2[0][nt], 0, 0, 0);
                    acc2[1][nt] = __builtin_amdgcn_mfma_f32_16x16x32_bf16(a1, bw2[ks * 2 + nt], acc2[1][nt], 0, 0, 0);
                }
            }
            const int p0w = wv * 32;
            #pragma unroll
            for (int nt = 0; nt < 2; ++nt) {
                const int p = p0w + nt * 16 + ln16;
                const float bb = canon[CAN_B2 + p];
                #pragma unroll
                for (int mt = 0; mt < 2; ++mt)
                    #pragma unroll
                    for (int r = 0; r < 4; ++r) {
                        const int row = mt * 16 + qr * 4 + r;
                        const float pm = pmf2[cur][row];
                        ol[row][p] = (acc2[mt][nt][r] + bb) * pm;
                    }
            }
        }
        if (t < RPB) pmf2[nxt][t] = (wmn && wmi && wsl) ? 1.f : 0.f;

        __syncthreads();  // D: ol + pmf2[nxt] complete

        // ---- coop store: out = z + O, full-line float4 per lane, nontemporal
        #pragma unroll
        for (int q = 0; q < 4; ++q) {
            const int row = 8 * q + lr;
            f32x4 o = *(const f32x4*)&ol[row][4 * c4];
            f32x4 ov = zq[q] + o;
            __builtin_nontemporal_store(ov, (f32x4*)&out[(row0 + row) * PD + 4 * c4]);
        }
    }
}

extern "C" void kernel_launch(void* const* d_in, const int* in_sizes, int n_in,
                              void* d_out, int out_size, void* d_ws, size_t ws_size,
                              hipStream_t stream) {
    const void* x        = d_in[0];
    const void* pair_rep = d_in[1];
    const void* mask     = d_in[2];
    const int*  nbr      = (const int*)d_in[3];
    const void* slot     = d_in[4];
    float* out = (float*)d_out;

    int*   flags = (int*)d_ws;
    float* canon = (float*)((char*)d_ws + 64);
    short* bw    = (short*)((char*)d_ws + BW_OFF);
    const short* wxt = bw + WXT_OFF;
    const short* w1t = bw + W1T_OFF;
    const short* w2t = bw + W2T_OFF;
    unsigned short* projb = (unsigned short*)((char*)d_ws + PROJ_OFF);

    detect_kernel<<<1, 256, 0, stream>>>(x, pair_rep, mask, slot, flags);
    prep_kernel<<<(CAN_TOTAL + BW_TOTAL + 255) / 256, 256, 0, stream>>>(
        d_in[5], d_in[6], d_in[7], d_in[8], d_in[9], d_in[10], d_in[11],
        d_in[12], d_in[13], flags, canon, bw);
    ln_proj_mfma<<<N_TOK / TPB_LN, 256, 0, stream>>>(x, canon, wxt, flags, projb);
    pair_kernel<<<(N_TOK * KNB) / (RPB * TILES_PER_BLK), 256, 0, stream>>>(
        pair_rep, mask, nbr, slot, canon, w1t, w2t, projb, flags, out);
}

// Round 15
// 305.422 us; speedup vs baseline: 1.5979x; 1.0793x over previous
//
#include <hip/hip_runtime.h>
#include <stdint.h>

#define N_TOK 4096
#define TD 384
#define KNB 64
#define PD 128
#define HD 256
#define NPROJ 256  // 2*PD
#define RPB 32     // rows per tile
#define TPB_LN 16  // tokens per block in ln kernel
#define TILES_PER_BLK 16

// ---- workspace layout (bytes) ----
// [0,64) int flags[16]; [64,661056) f32 canon; [663552,991232) bf16 weights;
// [1<<20, +2MB) projb bf16 [4096][256]
#define CAN_LN_G 0
#define CAN_LN_B 384
#define CAN_WX   768
#define CAN_T_G  99072
#define CAN_T_B  99200
#define CAN_W1   99328
#define CAN_B1   132096
#define CAN_W2   132352
#define CAN_B2   165120
#define CAN_TOTAL 165248

#define BW_OFF   663552
#define WXT_OFF  0        // WxT [256][384]
#define W1T_OFF  98304    // W1T [256][128]
#define W2T_OFF  131072   // W2T [128][256]
#define BW_TOTAL 163840
#define PROJ_OFF (1 << 20)

typedef __attribute__((ext_vector_type(8))) short bf16x8;
typedef __attribute__((ext_vector_type(4))) short s16x4;
typedef __attribute__((ext_vector_type(4))) float f32x4;
typedef __attribute__((ext_vector_type(2))) unsigned int u32x2;
typedef __attribute__((ext_vector_type(4))) unsigned int u32x4;

static __device__ __forceinline__ float bf2f(unsigned short u) {
    return __uint_as_float(((unsigned int)u) << 16);
}
static __device__ __forceinline__ unsigned short f2bf(float f) {
    unsigned int x = __float_as_uint(f);
    return (unsigned short)((x + 0x7FFFu + ((x >> 16) & 1u)) >> 16);
}
static __device__ __forceinline__ float loadf(const void* p, int mode, int i) {
    return mode ? bf2f(((const unsigned short*)p)[i]) : ((const float*)p)[i];
}
// raw word of a bool element (any storage mode); nonzero == true for all modes
static __device__ __forceinline__ unsigned int flag_word(const void* p, int mode, int i) {
    if (mode == 0) return ((const unsigned int*)p)[i];
    if (mode == 1) return (unsigned int)((const unsigned char*)p)[i];
    if (mode == 2) return (unsigned int)((const unsigned short*)p)[i];
    return ((const unsigned int*)p)[i];
}
static __device__ __forceinline__ bool plaus16(unsigned int h) {
    if (h == 0u) return true;
    unsigned int e = (h >> 7) & 0xFFu;
    return (e >= 0x60u && e <= 0x9Fu);
}

__global__ __launch_bounds__(256) void detect_kernel(
        const void* __restrict__ x, const void* __restrict__ pair_rep,
        const void* __restrict__ mask, const void* __restrict__ slot,
        int* __restrict__ flags) {
    const int t = threadIdx.x;
    const int wave = t >> 6, lane = t & 63;
    if (wave < 2) {
        const unsigned int* w = (const unsigned int*)(wave == 0 ? x : pair_rep);
        unsigned int v = w[lane];
        bool pl = plaus16(v & 0xFFFFu) && plaus16(v >> 16);
        unsigned long long b = __ballot(pl);
        if (lane == 0) flags[2 + wave] = (__popcll(b) >= 56) ? 1 : 0;
    } else {
        const unsigned int* w = (const unsigned int*)(wave == 2 ? mask : slot);
        bool ok01 = true, okbf = true, anybf_lo = false;
        #pragma unroll
        for (int j = 0; j < 4; ++j) {
            unsigned int v = w[lane * 4 + j];
            if (v > 1u) ok01 = false;
            unsigned int h0 = v & 0xFFFFu, h1 = v >> 16;
            if (!(h0 == 0u || h0 == 0x3F80u)) okbf = false;
            if (!(h1 == 0u || h1 == 0x3F80u)) okbf = false;
            if (h0 == 0x3F80u) anybf_lo = true;
        }
        unsigned long long b01 = __ballot(ok01);
        unsigned long long bbf = __ballot(okbf);
        unsigned long long bev = __ballot(anybf_lo);
        if (lane == 0) {
            int mode;
            if (b01 == ~0ull) mode = 0;
            else if (bbf == ~0ull) mode = (bev != 0ull) ? 2 : 3;
            else mode = 1;
            flags[wave - 2] = mode;
        }
    }
}

// f32 canon of 9 weight tensors + bf16 transposed Wx/W1/W2, one kernel.
__global__ __launch_bounds__(256) void prep_kernel(
        const void* p0, const void* p1, const void* p2, const void* p3,
        const void* p4, const void* p5, const void* p6, const void* p7,
        const void* p8, const int* __restrict__ flags,
        float* __restrict__ dstf, short* __restrict__ dstb) {
    const int mode = flags[2];
    int e = blockIdx.x * 256 + threadIdx.x;
    if (e < CAN_TOTAL) {
        const int offs[9] = {CAN_LN_G, CAN_LN_B, CAN_WX, CAN_T_G, CAN_T_B,
                             CAN_W1, CAN_B1, CAN_W2, CAN_B2};
        int s = 0;
        #pragma unroll
        for (int i = 1; i < 9; ++i) if (e >= offs[i]) s = i;
        const int local = e - offs[s];
        const void* p = (s == 0) ? p0 : (s == 1) ? p1 : (s == 2) ? p2 :
                        (s == 3) ? p3 : (s == 4) ? p4 : (s == 5) ? p5 :
                        (s == 6) ? p6 : (s == 7) ? p7 : p8;
        dstf[e] = loadf(p, mode, local);
    } else {
        int e2 = e - CAN_TOTAL;
        if (e2 >= BW_TOTAL) return;
        int src; const void* p;
        if (e2 < W1T_OFF)      { int n = e2 / TD, k = e2 - n * TD;           p = p2; src = k * NPROJ + n; }
        else if (e2 < W2T_OFF) { int l = e2 - W1T_OFF; int n = l >> 7, k = l & 127; p = p5; src = k * HD + n; }
        else                   { int l = e2 - W2T_OFF; int n = l >> 8, k = l & 255; p = p7; src = k * PD + n; }
        dstb[e2] = (short)f2bf(loadf(p, mode, src));
    }
}

// LN over TD=384 for 16 tokens, then proj = xn @ Wx via MFMA; output bf16.
__global__ __launch_bounds__(256) void ln_proj_mfma(
        const void* __restrict__ x,
        const float* __restrict__ canon,
        const short* __restrict__ wxt,
        const int* __restrict__ flags,
        unsigned short* __restrict__ projb) {
    __shared__ __align__(16) short xnb[TPB_LN][TD + 8];
    const int t = threadIdx.x, wv = t >> 6, lane = t & 63;
    const int tok0 = blockIdx.x * TPB_LN;
    const int xm = flags[2];

    float g[6], bv[6];
    #pragma unroll
    for (int j = 0; j < 6; ++j) {
        g[j]  = canon[CAN_LN_G + lane + 64 * j];
        bv[j] = canon[CAN_LN_B + lane + 64 * j];
    }
    #pragma unroll
    for (int rr = 0; rr < TPB_LN / 4; ++rr) {
        const int r = wv * (TPB_LN / 4) + rr;
        float v[6], s = 0.f, sq = 0.f;
        #pragma unroll
        for (int j = 0; j < 6; ++j) {
            v[j] = loadf(x, xm, (tok0 + r) * TD + lane + 64 * j);
            s += v[j]; sq += v[j] * v[j];
        }
        #pragma unroll
        for (int off = 32; off > 0; off >>= 1) {
            s += __shfl_down(s, off); sq += __shfl_down(sq, off);
        }
        s = __shfl(s, 0); sq = __shfl(sq, 0);
        const float mu = s * (1.f / TD);
        const float var = sq * (1.f / TD) - mu * mu;
        const float rs = rsqrtf(var + 1e-5f);
        #pragma unroll
        for (int j = 0; j < 6; ++j)
            xnb[r][lane + 64 * j] = (short)f2bf((v[j] - mu) * rs * g[j] + bv[j]);
    }
    __syncthreads();

    const int qr = lane >> 4, ln16 = lane & 15;
    const int n0 = wv * 64;
    f32x4 acc[4];
    #pragma unroll
    for (int nt = 0; nt < 4; ++nt) acc[nt] = f32x4{0.f, 0.f, 0.f, 0.f};
    #pragma unroll
    for (int ks = 0; ks < 12; ++ks) {
        const int k0 = ks * 32 + qr * 8;
        bf16x8 a = *(const bf16x8*)&xnb[ln16][k0];
        #pragma unroll
        for (int nt = 0; nt < 4; ++nt) {
            bf16x8 b = *(const bf16x8*)(wxt + (n0 + nt * 16 + ln16) * TD + k0);
            acc[nt] = __builtin_amdgcn_mfma_f32_16x16x32_bf16(a, b, acc[nt], 0, 0, 0);
        }
    }
    #pragma unroll
    for (int nt = 0; nt < 4; ++nt) {
        const int c = n0 + nt * 16 + ln16;
        #pragma unroll
        for (int r = 0; r < 4; ++r)
            projb[(tok0 + qr * 4 + r) * NPROJ + c] = f2bf(acc[nt][r]);
    }
}

// Persistent pipelined pair kernel. Linear-I/O + register-resident weights +
// fused z-LN (r10: 118us, VGPR 128, FETCH 82MB). This round:
//   1) pair_rep NT prefetch issued right after barrier A (no idxq dependency)
//      -> HBM latency (~900cy) hides behind phase4+phase5+store instead of
//      only phase5+store. projb gathers stay at post-C (L2-short).
//   2) TILES_PER_BLK 8->16, grid 512 = exactly 2 blocks/CU: one generation,
//      prologue paid once, weight loads amortized 2x.
//   (256,2) launch bounds preserved — r7/r8 lesson: tighter caps trigger
//   weight-load rematerialization (FETCH 640/335MB). Remat tripwire: FETCH
//   must stay ~82MB.
__global__ __launch_bounds__(256, 2) void pair_kernel(
        const void* __restrict__ pair_rep,
        const void* __restrict__ mask,
        const int*  __restrict__ nbr,
        const void* __restrict__ slot,
        const float* __restrict__ canon,
        const short* __restrict__ w1t,
        const short* __restrict__ w2t,
        const unsigned short* __restrict__ projb,
        const int* __restrict__ flags,
        float* __restrict__ out) {
    __shared__ __align__(16) short znb[RPB][PD + 8];   //  8.7 KB LN(z) bf16
    __shared__ __align__(16) float ol[RPB][PD + 4];    // 16.9 KB transition out f32
    __shared__ __align__(16) short Hb[RPB][HD + 8];    // 16.9 KB relu hidden bf16
    __shared__ float pmf2[2][RPB];

    const int t = threadIdx.x;
    const int wv = t >> 6, lane = t & 63, qr = lane >> 4, ln16 = lane & 15;
    const int lr = t >> 5;        // linear row slot 0..7
    const int c4 = t & 31;        // float4 column chunk (cols 4*c4 .. 4*c4+3)
    const int mmode = flags[0], smode = flags[1], prm = flags[3];

    // ---- persistent B-fragments (loaded once; live across the whole tile loop)
    bf16x8 bw1[16];   // phase-4 W1T frags: [ks*4+nt]
    bf16x8 bw2[16];   // phase-5 W2T frags: [ks*2+nt]
    #pragma unroll
    for (int ks = 0; ks < 4; ++ks)
        #pragma unroll
        for (int nt = 0; nt < 4; ++nt)
            bw1[ks * 4 + nt] = *(const bf16x8*)(
                w1t + (wv * 64 + nt * 16 + ln16) * PD + ks * 32 + qr * 8);
    #pragma unroll
    for (int ks = 0; ks < 8; ++ks)
        #pragma unroll
        for (int nt = 0; nt < 2; ++nt)
            bw2[ks * 2 + nt] = *(const bf16x8*)(
                w2t + (wv * 32 + nt * 16 + ln16) * HD + ks * 32 + qr * 8);

    // per-thread LN params for cols 4*c4..4*c4+3 (loop-invariant)
    float tg[4], tb[4];
    #pragma unroll
    for (int e = 0; e < 4; ++e) {
        tg[e] = canon[CAN_T_G + 4 * c4 + e];
        tb[e] = canon[CAN_T_B + 4 * c4 + e];
    }

    // prefetch registers (raw words, converted at consume)
    int idxq[4], mIdx = 0;
    u32x4 pru[4];                 // pair_rep: f32 mode uses 4 words, bf16 mode 2
    u32x2 pgu[4];                 // gathered xp1 row chunk (4 bf16)
    u32x2 x2u;                    // xp2 chunk (4 bf16), same for all rows of tile
    unsigned int wmn = 0, wmi = 0, wsl = 0;

    const int tile0 = blockIdx.x * TILES_PER_BLK;

    // ---------- prologue: full prefetch of tile0 ----------
    {
        const int row0 = tile0 * RPB, n = row0 >> 6, k0 = row0 & (KNB - 1);
        #pragma unroll
        for (int q = 0; q < 4; ++q) idxq[q] = nbr[n * KNB + k0 + 8 * q + lr];
        x2u = *(const u32x2*)(projb + n * NPROJ + PD + 4 * c4);
        #pragma unroll
        for (int q = 0; q < 4; ++q)
            pgu[q] = *(const u32x2*)(projb + idxq[q] * NPROJ + 4 * c4);
        if (prm) {
            const unsigned short* pr = (const unsigned short*)pair_rep;
            #pragma unroll
            for (int q = 0; q < 4; ++q) {
                u32x2 v = __builtin_nontemporal_load(
                    (const u32x2*)(pr + (row0 + 8 * q + lr) * PD + 4 * c4));
                pru[q][0] = v[0]; pru[q][1] = v[1];
            }
        } else {
            const float* pr = (const float*)pair_rep;
            #pragma unroll
            for (int q = 0; q < 4; ++q)
                pru[q] = __builtin_nontemporal_load(
                    (const u32x4*)(pr + (row0 + 8 * q + lr) * PD + 4 * c4));
        }
        if (t < RPB) {
            mIdx = nbr[n * KNB + k0 + t];
            wmn = flag_word(mask, mmode, n);
            wmi = flag_word(mask, mmode, mIdx);
            wsl = flag_word(slot, smode, n * KNB + k0 + t);
            pmf2[0][t] = (wmn && wmi && wsl) ? 1.f : 0.f;
        }
    }
    __syncthreads();  // pmf2[0] visible before first phase-2 read

    #pragma unroll 1
    for (int i = 0; i < TILES_PER_BLK; ++i) {
        const int tile = tile0 + i;
        const int cur = i & 1, nxt = cur ^ 1;
        const int row0 = tile * RPB;
        const int tn = (i + 1 < TILES_PER_BLK) ? tile + 1 : tile;  // clamp (dup loads unused)
        const int row0n = tn * RPB, nn = row0n >> 6, k0n = row0n & (KNB - 1);

        // ---- phase 2 (+fused LN): z = (pair + xp2 + xp1[idx])*pm; row stats via
        //      half-wave shfl_xor on f32 z; write LN(z) bf16 to znb; keep z in zq.
        f32x4 zq[4];
        {
            float x2v[4];
            x2v[0] = bf2f((unsigned short)(x2u[0] & 0xFFFFu));
            x2v[1] = bf2f((unsigned short)(x2u[0] >> 16));
            x2v[2] = bf2f((unsigned short)(x2u[1] & 0xFFFFu));
            x2v[3] = bf2f((unsigned short)(x2u[1] >> 16));
            #pragma unroll
            for (int q = 0; q < 4; ++q) {
                const int row = 8 * q + lr;
                const float pm = pmf2[cur][row];
                float a[4], gg[4];
                gg[0] = bf2f((unsigned short)(pgu[q][0] & 0xFFFFu));
                gg[1] = bf2f((unsigned short)(pgu[q][0] >> 16));
                gg[2] = bf2f((unsigned short)(pgu[q][1] & 0xFFFFu));
                gg[3] = bf2f((unsigned short)(pgu[q][1] >> 16));
                if (prm) {
                    a[0] = bf2f((unsigned short)(pru[q][0] & 0xFFFFu));
                    a[1] = bf2f((unsigned short)(pru[q][0] >> 16));
                    a[2] = bf2f((unsigned short)(pru[q][1] & 0xFFFFu));
                    a[3] = bf2f((unsigned short)(pru[q][1] >> 16));
                } else {
                    a[0] = __uint_as_float(pru[q][0]);
                    a[1] = __uint_as_float(pru[q][1]);
                    a[2] = __uint_as_float(pru[q][2]);
                    a[3] = __uint_as_float(pru[q][3]);
                }
                float s = 0.f, sq = 0.f;
                #pragma unroll
                for (int e = 0; e < 4; ++e) {
                    const float z = (a[e] + x2v[e] + gg[e]) * pm;
                    zq[q][e] = z;
                    s += z; sq += z * z;
                }
                // reduce over the 32 lanes owning this row (offsets <32 stay in-group)
                #pragma unroll
                for (int off = 16; off > 0; off >>= 1) {
                    s  += __shfl_xor(s, off);
                    sq += __shfl_xor(sq, off);
                }
                const float mu = s * (1.f / PD);
                const float var = sq * (1.f / PD) - mu * mu;
                const float rs = rsqrtf(var + 1e-5f);
                s16x4 zs;
                #pragma unroll
                for (int e = 0; e < 4; ++e)
                    zs[e] = (short)f2bf((zq[q][e] - mu) * rs * tg[e] + tb[e]);
                *(s16x4*)&znb[row][4 * c4] = zs;
            }
        }

        // issue next-tile index loads (consumed at sync C prefetch)
        #pragma unroll
        for (int q = 0; q < 4; ++q) idxq[q] = nbr[nn * KNB + k0n + 8 * q + lr];
        if (t < RPB) mIdx = nbr[nn * KNB + k0n + t];

        __syncthreads();  // A: znb complete; also fences prev-iter ol reads vs phase 5

        // ---- EARLY prefetch: pair_rep stream for tile tn (no idxq dependency).
        //      Issued before phase 4 so HBM latency hides behind 4+5+store.
        if (prm) {
            const unsigned short* pr = (const unsigned short*)pair_rep;
            #pragma unroll
            for (int q = 0; q < 4; ++q) {
                u32x2 v = __builtin_nontemporal_load(
                    (const u32x2*)(pr + (row0n + 8 * q + lr) * PD + 4 * c4));
                pru[q][0] = v[0]; pru[q][1] = v[1];
            }
        } else {
            const float* pr = (const float*)pair_rep;
            #pragma unroll
            for (int q = 0; q < 4; ++q)
                pru[q] = __builtin_nontemporal_load(
                    (const u32x4*)(pr + (row0n + 8 * q + lr) * PD + 4 * c4));
        }

        // ---- phase 4: H = relu(zn @ W1 + b1)  (B-frags in regs, no global loads)
        {
            f32x4 acc1[2][4];
            #pragma unroll
            for (int mt = 0; mt < 2; ++mt)
                #pragma unroll
                for (int nt = 0; nt < 4; ++nt) acc1[mt][nt] = f32x4{0.f, 0.f, 0.f, 0.f};
            #pragma unroll
            for (int ks = 0; ks < 4; ++ks) {
                const int k0 = ks * 32 + qr * 8;
                bf16x8 a0 = *(const bf16x8*)&znb[ln16][k0];
                bf16x8 a1 = *(const bf16x8*)&znb[16 + ln16][k0];
                #pragma unroll
                for (int nt = 0; nt < 4; ++nt) {
                    acc1[0][nt] = __builtin_amdgcn_mfma_f32_16x16x32_bf16(a0, bw1[ks * 4 + nt], acc1[0][nt], 0, 0, 0);
                    acc1[1][nt] = __builtin_amdgcn_mfma_f32_16x16x32_bf16(a1, bw1[ks * 4 + nt], acc1[1][nt], 0, 0, 0);
                }
            }
            const int n0 = wv * 64;
            #pragma unroll
            for (int nt = 0; nt < 4; ++nt) {
                const int c = n0 + nt * 16 + ln16;
                const float bb = canon[CAN_B1 + c];
                #pragma unroll
                for (int mt = 0; mt < 2; ++mt)
                    #pragma unroll
                    for (int r = 0; r < 4; ++r) {
                        const float h = acc1[mt][nt][r] + bb;
                        Hb[mt * 16 + qr * 4 + r][c] = (short)f2bf(h > 0.f ? h : 0.f);
                    }
            }
        }
        __syncthreads();  // C: Hb complete

        // ---- remaining prefetch for tile tn (projb gathers need idxq; L2-short)
        x2u = *(const u32x2*)(projb + nn * NPROJ + PD + 4 * c4);
        #pragma unroll
        for (int q = 0; q < 4; ++q)
            pgu[q] = *(const u32x2*)(projb + idxq[q] * NPROJ + 4 * c4);
        if (t < RPB) {
            wmn = flag_word(mask, mmode, nn);
            wmi = flag_word(mask, mmode, mIdx);
            wsl = flag_word(slot, smode, nn * KNB + k0n + t);
        }

        // ---- phase 5: O = H @ W2 + b2; stage O*pm into ol (f32, MFMA layout)
        {
            f32x4 acc2[2][2];
            #pragma unroll
            for (int mt = 0; mt < 2; ++mt)
                #pragma unroll
                for (int nt = 0; nt < 2; ++nt) acc2[mt][nt] = f32x4{0.f, 0.f, 0.f, 0.f};
            #pragma unroll
            for (int ks = 0; ks < 8; ++ks) {
                const int k0 = ks * 32 + qr * 8;
                bf16x8 a0 = *(const bf16x8*)&Hb[ln16][k0];
                bf16x8 a1 = *(const bf16x8*)&Hb[16 + ln16][k0];
                #pragma unroll
                for (int nt = 0; nt < 2; ++nt) {
                    acc2[0][nt] = __builtin_amdgcn_mfma_f32_16x16x32_bf16(a0, bw2[ks * 2 + nt], acc2[0][nt], 0, 0, 0);
                    acc2[1][nt] = __builtin_amdgcn_mfma_f32_16x16x32_bf16(a1, bw2[ks * 2 + nt], acc2[1][nt], 0, 0, 0);
                }
            }
            const int p0w = wv * 32;
            #pragma unroll
            for (int nt = 0; nt < 2; ++nt) {
                const int p = p0w + nt * 16 + ln16;
                const float bb = canon[CAN_B2 + p];
                #pragma unroll
                for (int mt = 0; mt < 2; ++mt)
                    #pragma unroll
                    for (int r = 0; r < 4; ++r) {
                        const int row = mt * 16 + qr * 4 + r;
                        const float pm = pmf2[cur][row];
                        ol[row][p] = (acc2[mt][nt][r] + bb) * pm;
                    }
            }
        }
        if (t < RPB) pmf2[nxt][t] = (wmn && wmi && wsl) ? 1.f : 0.f;

        __syncthreads();  // D: ol + pmf2[nxt] complete

        // ---- coop store: out = z + O, full-line float4 per lane, nontemporal
        #pragma unroll
        for (int q = 0; q < 4; ++q) {
            const int row = 8 * q + lr;
            f32x4 o = *(const f32x4*)&ol[row][4 * c4];
            f32x4 ov = zq[q] + o;
            __builtin_nontemporal_store(ov, (f32x4*)&out[(row0 + row) * PD + 4 * c4]);
        }
    }
}

extern "C" void kernel_launch(void* const* d_in, const int* in_sizes, int n_in,
                              void* d_out, int out_size, void* d_ws, size_t ws_size,
                              hipStream_t stream) {
    const void* x        = d_in[0];
    const void* pair_rep = d_in[1];
    const void* mask     = d_in[2];
    const int*  nbr      = (const int*)d_in[3];
    const void* slot     = d_in[4];
    float* out = (float*)d_out;

    int*   flags = (int*)d_ws;
    float* canon = (float*)((char*)d_ws + 64);
    short* bw    = (short*)((char*)d_ws + BW_OFF);
    const short* wxt = bw + WXT_OFF;
    const short* w1t = bw + W1T_OFF;
    const short* w2t = bw + W2T_OFF;
    unsigned short* projb = (unsigned short*)((char*)d_ws + PROJ_OFF);

    detect_kernel<<<1, 256, 0, stream>>>(x, pair_rep, mask, slot, flags);
    prep_kernel<<<(CAN_TOTAL + BW_TOTAL + 255) / 256, 256, 0, stream>>>(
        d_in[5], d_in[6], d_in[7], d_in[8], d_in[9], d_in[10], d_in[11],
        d_in[12], d_in[13], flags, canon, bw);
    ln_proj_mfma<<<N_TOK / TPB_LN, 256, 0, stream>>>(x, canon, wxt, flags, projb);
    pair_kernel<<<(N_TOK * KNB) / (RPB * TILES_PER_BLK), 256, 0, stream>>>(
        pair_rep, mask, nbr, slot, canon, w1t, w2t, projb, flags, out);
}